// Round 21
// baseline (87.272 us; speedup 1.0000x reference)
//
#include <hip/hip_runtime.h>
#include <math.h>

#define FF 256
#define CC 100000
#define PMARG 0.2f
#define NMARG 0.3f
#define NCT 6250                 // col-tiles of 16 (6250*16 == CC exactly)
#define NGB 3125                 // gemm blocks: 2 ct x 4 k-quarters (8 waves)
#define W_A 0                    // ws floats: A-pack bf16 frags (32KB)
#define W_GRAM 8192              // Gram 64x64 f32
#define W_SE 12288               // 64 row exp-sums
#define W_PART 12352             // per-ct exp partials: NCT*64 floats

typedef __attribute__((ext_vector_type(8))) short short8;   // 8 bf16 = 4 VGPR
typedef __attribute__((ext_vector_type(4))) float f32x4;

__device__ __forceinline__ float wredf(float v) {
#pragma unroll
    for (int s = 1; s < 64; s <<= 1) v += __shfl_xor(v, s, 64);
    return v;
}
__device__ __forceinline__ short f2bf(float f) {
    unsigned u = __float_as_uint(f);
    unsigned r = (u + 0x7fffu + ((u >> 16) & 1u)) >> 16;
    return (short)r;
}
__device__ __forceinline__ short8 pack8(float4 a, float4 b) {
    short8 o;
    o[0] = f2bf(a.x); o[1] = f2bf(a.y); o[2] = f2bf(a.z); o[3] = f2bf(a.w);
    o[4] = f2bf(b.x); o[5] = f2bf(b.y); o[6] = f2bf(b.z); o[7] = f2bf(b.w);
    return o;
}
__device__ __forceinline__ short8 pack8v(f32x4 a, f32x4 b) {
    short8 o;
    o[0] = f2bf(a[0]); o[1] = f2bf(a[1]); o[2] = f2bf(a[2]); o[3] = f2bf(a[3]);
    o[4] = f2bf(b[0]); o[5] = f2bf(b[1]); o[6] = f2bf(b[2]); o[7] = f2bf(b[3]);
    return o;
}
__device__ __forceinline__ float dot4(float4 a, float4 b) {
    return a.x * b.x + a.y * b.y + a.z * b.z + a.w * b.w;
}
__device__ __forceinline__ bool mask_at(const void* p, int idx, int mode) {
    if (mode == 0) return ((const int*)p)[idx] != 0;
    if (mode == 1) return ((const float*)p)[idx] != 0.f;
    return ((const unsigned char*)p)[idx] != 0;
}

// blocks 0..63: Gram row b (f32, accuracy-critical); block 64: A-pack
__global__ __launch_bounds__(256) void k_prep(const float* __restrict__ in,
                                              float* __restrict__ ws) {
    int tid = threadIdx.x;
    int b = blockIdx.x;
    const float4* __restrict__ in4 = (const float4*)in;
    if (b < 64) {
        __shared__ float sS[256];
        int r = b, c = tid & 63, part = tid >> 6;
        float s = 0.f;
#pragma unroll
        for (int i = 0; i < 16; ++i) {
            int kq = part * 16 + i;
            s += dot4(in4[r * 64 + kq], in4[c * 64 + kq]);
        }
        sS[tid] = s;
        __syncthreads();
        if (tid < 64)
            ws[W_GRAM + r * 64 + tid] =
                sS[tid] + sS[64 + tid] + sS[128 + tid] + sS[192 + tid];
        return;
    }
    short8* __restrict__ wsa = (short8*)(ws + W_A);
#pragma unroll
    for (int i = 0; i < 8; ++i) {
        int idx = i * 256 + tid;          // (mt*8+ks)*64 + lane
        int lane = idx & 63;
        int ks = (idx >> 6) & 7;
        int mt = idx >> 9;
        int row = mt * 16 + (lane & 15);
        int kq = ks * 8 + (lane >> 4) * 2;
        wsa[idx] = pack8(in4[row * 64 + kq], in4[row * 64 + kq + 1]);
    }
}

// 4-way split-K GEMM, single pass over V-f32: block = 8 waves = 2 ct x 4
// k-quarters. Each wave: 4 loads (half of R20's chain), 8 MFMA. Waves kq=1..3
// deposit accumulators in LDS (24KB), one barrier, kq=0 wave sums + epilogue.
// V read once, no intermediate buffer.
__global__ __launch_bounds__(512) void k_gemm5b(const float* __restrict__ V,
                                                const float* __restrict__ ws_in,
                                                float* __restrict__ logits,
                                                float* __restrict__ ws) {
    __shared__ f32x4 sAcc[2][3][64][4];   // 24KB: partner-wave accumulators
    int tid = threadIdx.x;
    int lane = tid & 63, w = tid >> 6;    // 8 waves
    int ctl = w >> 2, kq = w & 3;         // ct-local, k-quarter
    int ct = blockIdx.x * 2 + ctl;        // 0..6249, all fully valid
    int g = lane >> 4, c4 = lane & 15;

    // lane reads V[ct*16+c4][(kq*2+ksl)*32 + g*8 .. +8], ksl=0..1
    const f32x4* __restrict__ vp =
        (const f32x4*)V + (size_t)(ct * 16 + c4) * 64 + kq * 16 + g * 2;
    f32x4 bv[2][2];
#pragma unroll
    for (int ksl = 0; ksl < 2; ++ksl) {
        bv[ksl][0] = vp[ksl * 8];
        bv[ksl][1] = vp[ksl * 8 + 1];
    }

    const short8* __restrict__ ap = (const short8*)(ws_in + W_A) + lane;
    f32x4 acc[4];
#pragma unroll
    for (int mt = 0; mt < 4; ++mt) acc[mt] = (f32x4){0.f, 0.f, 0.f, 0.f};
#pragma unroll
    for (int ksl = 0; ksl < 2; ++ksl) {
        int ks = kq * 2 + ksl;
        short8 bf = pack8v(bv[ksl][0], bv[ksl][1]);
#pragma unroll
        for (int mt = 0; mt < 4; ++mt) {
            short8 a = ap[(mt * 8 + ks) * 64];     // L1-hot, coalesced
            acc[mt] = __builtin_amdgcn_mfma_f32_16x16x32_bf16(a, bf, acc[mt],
                                                              0, 0, 0);
        }
    }

    // ---- combine k-quarters via LDS ----
    if (kq > 0) {
#pragma unroll
        for (int mt = 0; mt < 4; ++mt) sAcc[ctl][kq - 1][lane][mt] = acc[mt];
    }
    __syncthreads();
    if (kq > 0) return;
#pragma unroll
    for (int q = 0; q < 3; ++q)
#pragma unroll
        for (int mt = 0; mt < 4; ++mt) {
            f32x4 o = sAcc[ctl][q][lane][mt];
            acc[mt][0] += o[0]; acc[mt][1] += o[1];
            acc[mt][2] += o[2]; acc[mt][3] += o[3];
        }

    // ---- epilogue: stores + per-ct exp partials ----
    int col = ct * 16 + c4;
    float* __restrict__ P = ws + W_PART + (size_t)ct * 64;
#pragma unroll
    for (int mt = 0; mt < 4; ++mt)
#pragma unroll
        for (int r = 0; r < 4; ++r) {
            int row = mt * 16 + g * 4 + r;
            float lg = acc[mt][r];
            logits[(size_t)row * CC + col] = lg;
            float e = expf(lg);                    // |logit| <= ~19, safe
            e += __shfl_xor(e, 1, 64); e += __shfl_xor(e, 2, 64);
            e += __shfl_xor(e, 4, 64); e += __shfl_xor(e, 8, 64);
            if (c4 == 0) P[row] = e;               // deterministic
        }
}

// 64 blocks (one per batch row): deterministic reduce of exp partials
__global__ __launch_bounds__(256) void k_comb(const float* __restrict__ ws_in,
                                              float* __restrict__ ws) {
    __shared__ float sS[256];
    int row = blockIdx.x;
    int tid = threadIdx.x;
    const float* __restrict__ P = ws_in + W_PART;
    float s = 0.f;
    for (int b = tid; b < NCT; b += 256) s += P[(size_t)b * 64 + row];
    sS[tid] = s;
    __syncthreads();
    if (tid < 128) sS[tid] += sS[tid + 128];
    __syncthreads();
    if (tid < 64) {
        float v = sS[tid] + sS[tid + 64];
        v = wredf(v);
        if (tid == 0) ws[W_SE + row] = v;
    }
}

// 1 block x 256 threads: G in LDS, masks as per-lane 64-bit registers
__global__ __launch_bounds__(256) void k_final(const int* __restrict__ targets,
                                               const void* __restrict__ pmask,
                                               const void* __restrict__ nmask,
                                               const float* __restrict__ logits,
                                               const float* __restrict__ ws,
                                               float* __restrict__ out) {
    __shared__ float sG[4096];
    int tid = threadIdx.x;
    float myLogit = 0.f, mySe = 0.f;
    if (tid < 64) {
        int tgt = targets[tid];
        myLogit = logits[(size_t)tid * CC + tgt];
        mySe = ws[W_SE + tid];
    }
    {
        const float4* __restrict__ G4 = (const float4*)(ws + W_GRAM);
        float4* sG4 = (float4*)sG;
#pragma unroll
        for (int i = 0; i < 4; ++i) sG4[tid + i * 256] = G4[tid + i * 256];
    }
    __syncthreads();
    if (tid >= 64) return;
    int lane = tid;

    // mode detect (identical semantics to all prior rounds)
    const unsigned int* pw = (const unsigned int*)pmask;
    int okInt = 1, okFlt = 1;
#pragma unroll
    for (int i = 0; i < 16; ++i) {
        unsigned int wv = pw[lane * 16 + i];
        okInt = okInt && (wv <= 1u);
        okFlt = okFlt && (wv == 0u || wv == 0x3f800000u);
    }
    int mode = __all(okInt) ? 0 : (__all(okFlt) ? 1 : 2);

    // pack masks into per-lane 64-bit registers (no memory in j-loops)
    unsigned long long pmb = 0ull, nmb = 0ull;
    for (int j = 0; j < 64; ++j) {
        if (mask_at(pmask, lane * 64 + j, mode)) pmb |= 1ull << j;
        if (mask_at(nmask, lane * 64 + j, mode)) nmb |= 1ull << j;
    }

    float lse = logf(mySe);
    float nll = lse - myLogit;
    float rinv = rsqrtf(sG[lane * 64 + lane]);

    float minp = INFINITY, maxthd = -INFINITY;
    for (int j = 0; j < 64; ++j) {
        float rj = __shfl(rinv, j, 64);
        float sim = sG[lane * 64 + j] * rinv * rj;
        sim = fminf(1.f, fmaxf(-1.f, sim));
        if (j != lane) {
            bool pm = (pmb >> j) & 1ull;
            float ps = pm ? sim : 2.0f;
            minp = fminf(minp, ps);
            maxthd = fmaxf(maxthd, pm ? sim : -2.0f);   // sentinel 2.0 -> -2.0
        }
    }
    float n_thrd = minp - NMARG;
    float p_thrd = maxthd - PMARG;

    float hps = 0.f, hns = 0.f, hpc = 0.f, hnc = 0.f;
    for (int j = 0; j < 64; ++j) {
        float rj = __shfl(rinv, j, 64);
        float sim = sG[lane * 64 + j] * rinv * rj;
        sim = fminf(1.f, fmaxf(-1.f, sim));
        if (j != lane) {
            bool pm = (pmb >> j) & 1ull;
            bool nm = (nmb >> j) & 1ull;
            float ps = pm ? sim : 2.0f;
            float ns = nm ? sim : 2.0f;
            if (ps < p_thrd) { hps += log1pf(expf(-ps)); hpc += 1.f; }
            if (ns < n_thrd) { hns += log1pf(expf(-ns)); hnc += 1.f; }
        }
    }

    float snll = wredf(nll);
    float shps = wredf(hps);
    float shns = wredf(hns);
    float shpc = wredf(hpc);
    float shnc = wredf(hnc);
    if (lane == 0) {
        float bu = snll * (1.f / 64.f);
        float hp = shpc > 0.f ? shps / shpc : 0.f;
        float hn = shnc > 0.f ? shns / shnc : 0.f;
        out[0] = bu + hp + hn;
    }
}

extern "C" void kernel_launch(void* const* d_in, const int* in_sizes, int n_in,
                              void* d_out, int out_size, void* d_ws, size_t ws_size,
                              hipStream_t stream) {
    const float* inputs = (const float*)d_in[0];
    const int* targets  = (const int*)d_in[1];
    const void* pmask   = d_in[2];
    const void* nmask   = d_in[3];
    const float* V      = (const float*)d_in[4];
    float* out = (float*)d_out;      // out[0] = loss
    float* logits = out + 1;         // out[1..] = logits [64][100000] row-major
    float* ws = (float*)d_ws;        // A-pack | Gram | se | per-ct partials

    hipLaunchKernelGGL(k_prep, dim3(65), dim3(256), 0, stream, inputs, ws);
    hipLaunchKernelGGL(k_gemm5b, dim3(NGB), dim3(512), 0, stream,
                       V, ws, logits, ws);
    hipLaunchKernelGGL(k_comb, dim3(64), dim3(256), 0, stream, ws, ws);
    hipLaunchKernelGGL(k_final, dim3(1), dim3(256), 0, stream,
                       targets, pmask, nmask, logits, ws, out);
}

// Round 22
// 85.112 us; speedup vs baseline: 1.0254x; 1.0254x over previous
//
#include <hip/hip_runtime.h>
#include <math.h>

#define FF 256
#define CC 100000
#define PMARG 0.2f
#define NMARG 0.3f
#define NCT 6250                 // col-tiles of 16 (6250*16 == CC exactly)
#define NGB 3125                 // gemm blocks: 2 ct x 2 k-halves (4 waves)
#define W_A 0                    // ws floats: A-pack bf16 frags (32KB)
#define W_GRAM 8192              // Gram 64x64 f32
#define W_SE 12288               // 64 row exp-sums
#define W_PART 12352             // per-ct exp partials: NCT*64 floats

typedef __attribute__((ext_vector_type(8))) short short8;   // 8 bf16 = 4 VGPR
typedef __attribute__((ext_vector_type(4))) float f32x4;

__device__ __forceinline__ float wredf(float v) {
#pragma unroll
    for (int s = 1; s < 64; s <<= 1) v += __shfl_xor(v, s, 64);
    return v;
}
__device__ __forceinline__ short f2bf(float f) {
    unsigned u = __float_as_uint(f);
    unsigned r = (u + 0x7fffu + ((u >> 16) & 1u)) >> 16;
    return (short)r;
}
__device__ __forceinline__ short8 pack8(float4 a, float4 b) {
    short8 o;
    o[0] = f2bf(a.x); o[1] = f2bf(a.y); o[2] = f2bf(a.z); o[3] = f2bf(a.w);
    o[4] = f2bf(b.x); o[5] = f2bf(b.y); o[6] = f2bf(b.z); o[7] = f2bf(b.w);
    return o;
}
__device__ __forceinline__ short8 pack8v(f32x4 a, f32x4 b) {
    short8 o;
    o[0] = f2bf(a[0]); o[1] = f2bf(a[1]); o[2] = f2bf(a[2]); o[3] = f2bf(a[3]);
    o[4] = f2bf(b[0]); o[5] = f2bf(b[1]); o[6] = f2bf(b[2]); o[7] = f2bf(b[3]);
    return o;
}
__device__ __forceinline__ float dot4(float4 a, float4 b) {
    return a.x * b.x + a.y * b.y + a.z * b.z + a.w * b.w;
}
__device__ __forceinline__ bool mask_at(const void* p, int idx, int mode) {
    if (mode == 0) return ((const int*)p)[idx] != 0;
    if (mode == 1) return ((const float*)p)[idx] != 0.f;
    return ((const unsigned char*)p)[idx] != 0;
}

// blocks 0..63: Gram row b (f32, accuracy-critical); block 64: A-pack
__global__ __launch_bounds__(256) void k_prep(const float* __restrict__ in,
                                              float* __restrict__ ws) {
    int tid = threadIdx.x;
    int b = blockIdx.x;
    const float4* __restrict__ in4 = (const float4*)in;
    if (b < 64) {
        __shared__ float sS[256];
        int r = b, c = tid & 63, part = tid >> 6;
        float s = 0.f;
#pragma unroll
        for (int i = 0; i < 16; ++i) {
            int kq = part * 16 + i;
            s += dot4(in4[r * 64 + kq], in4[c * 64 + kq]);
        }
        sS[tid] = s;
        __syncthreads();
        if (tid < 64)
            ws[W_GRAM + r * 64 + tid] =
                sS[tid] + sS[64 + tid] + sS[128 + tid] + sS[192 + tid];
        return;
    }
    short8* __restrict__ wsa = (short8*)(ws + W_A);
#pragma unroll
    for (int i = 0; i < 8; ++i) {
        int idx = i * 256 + tid;          // (mt*8+ks)*64 + lane
        int lane = idx & 63;
        int ks = (idx >> 6) & 7;
        int mt = idx >> 9;
        int row = mt * 16 + (lane & 15);
        int kq = ks * 8 + (lane >> 4) * 2;
        wsa[idx] = pack8(in4[row * 64 + kq], in4[row * 64 + kq + 1]);
    }
}

// Split-K GEMM, single pass over V-f32: block = 4 waves = 2 ct x 2 k-halves.
// Each wave loads only ITS K-half (8 loads) of its ct's 16 V rows, does
// 16 MFMA; kh=1 wave deposits accumulators in LDS, one barrier, kh=0 wave
// sums + epilogue. V read once, no intermediate buffer, no producer pass.
__global__ __launch_bounds__(256) void k_gemm5(const float* __restrict__ V,
                                               const float* __restrict__ ws_in,
                                               float* __restrict__ logits,
                                               float* __restrict__ ws) {
    __shared__ f32x4 sAcc[2][64][4];      // 8KB: partner-wave accumulators
    int tid = threadIdx.x;
    int lane = tid & 63, w = tid >> 6;
    int ctl = w >> 1, kh = w & 1;         // ct-local, k-half
    int ct = blockIdx.x * 2 + ctl;        // 0..6249, all fully valid
    int g = lane >> 4, c4 = lane & 15;

    // lane reads V[ct*16+c4][(kh*4+ksl)*32 + g*8 .. +8], ksl=0..3
    const f32x4* __restrict__ vp =
        (const f32x4*)V + (size_t)(ct * 16 + c4) * 64 + kh * 32 + g * 2;
    f32x4 bv[4][2];
#pragma unroll
    for (int ksl = 0; ksl < 4; ++ksl) {
        bv[ksl][0] = vp[ksl * 8];
        bv[ksl][1] = vp[ksl * 8 + 1];
    }

    const short8* __restrict__ ap = (const short8*)(ws_in + W_A) + lane;
    f32x4 acc[4];
#pragma unroll
    for (int mt = 0; mt < 4; ++mt) acc[mt] = (f32x4){0.f, 0.f, 0.f, 0.f};
#pragma unroll
    for (int ksl = 0; ksl < 4; ++ksl) {
        short8 bf = pack8v(bv[ksl][0], bv[ksl][1]);
#pragma unroll
        for (int mt = 0; mt < 4; ++mt) {
            short8 a = ap[(mt * 8 + kh * 4 + ksl) * 64];   // L1-hot, coalesced
            acc[mt] = __builtin_amdgcn_mfma_f32_16x16x32_bf16(a, bf, acc[mt],
                                                              0, 0, 0);
        }
    }

    // ---- combine k-halves via LDS ----
    if (kh == 1) {
#pragma unroll
        for (int mt = 0; mt < 4; ++mt) sAcc[ctl][lane][mt] = acc[mt];
    }
    __syncthreads();
    if (kh == 1) return;
#pragma unroll
    for (int mt = 0; mt < 4; ++mt) {
        f32x4 o = sAcc[ctl][lane][mt];
        acc[mt][0] += o[0]; acc[mt][1] += o[1];
        acc[mt][2] += o[2]; acc[mt][3] += o[3];
    }

    // ---- epilogue: stores + per-ct exp partials ----
    int col = ct * 16 + c4;
    float* __restrict__ P = ws + W_PART + (size_t)ct * 64;
#pragma unroll
    for (int mt = 0; mt < 4; ++mt)
#pragma unroll
        for (int r = 0; r < 4; ++r) {
            int row = mt * 16 + g * 4 + r;
            float lg = acc[mt][r];
            logits[(size_t)row * CC + col] = lg;
            float e = expf(lg);                    // |logit| <= ~19, safe
            e += __shfl_xor(e, 1, 64); e += __shfl_xor(e, 2, 64);
            e += __shfl_xor(e, 4, 64); e += __shfl_xor(e, 8, 64);
            if (c4 == 0) P[row] = e;               // deterministic
        }
}

// 64 blocks (one per batch row): deterministic reduce of exp partials
__global__ __launch_bounds__(256) void k_comb(const float* __restrict__ ws_in,
                                              float* __restrict__ ws) {
    __shared__ float sS[256];
    int row = blockIdx.x;
    int tid = threadIdx.x;
    const float* __restrict__ P = ws_in + W_PART;
    float s = 0.f;
    for (int b = tid; b < NCT; b += 256) s += P[(size_t)b * 64 + row];
    sS[tid] = s;
    __syncthreads();
    if (tid < 128) sS[tid] += sS[tid + 128];
    __syncthreads();
    if (tid < 64) {
        float v = sS[tid] + sS[tid + 64];
        v = wredf(v);
        if (tid == 0) ws[W_SE + row] = v;
    }
}

// 1 block x 256 threads: G in LDS, masks as per-lane 64-bit registers
__global__ __launch_bounds__(256) void k_final(const int* __restrict__ targets,
                                               const void* __restrict__ pmask,
                                               const void* __restrict__ nmask,
                                               const float* __restrict__ logits,
                                               const float* __restrict__ ws,
                                               float* __restrict__ out) {
    __shared__ float sG[4096];
    int tid = threadIdx.x;
    float myLogit = 0.f, mySe = 0.f;
    if (tid < 64) {
        int tgt = targets[tid];
        myLogit = logits[(size_t)tid * CC + tgt];
        mySe = ws[W_SE + tid];
    }
    {
        const float4* __restrict__ G4 = (const float4*)(ws + W_GRAM);
        float4* sG4 = (float4*)sG;
#pragma unroll
        for (int i = 0; i < 4; ++i) sG4[tid + i * 256] = G4[tid + i * 256];
    }
    __syncthreads();
    if (tid >= 64) return;
    int lane = tid;

    // mode detect (identical semantics to all prior rounds)
    const unsigned int* pw = (const unsigned int*)pmask;
    int okInt = 1, okFlt = 1;
#pragma unroll
    for (int i = 0; i < 16; ++i) {
        unsigned int wv = pw[lane * 16 + i];
        okInt = okInt && (wv <= 1u);
        okFlt = okFlt && (wv == 0u || wv == 0x3f800000u);
    }
    int mode = __all(okInt) ? 0 : (__all(okFlt) ? 1 : 2);

    // pack masks into per-lane 64-bit registers (no memory in j-loops)
    unsigned long long pmb = 0ull, nmb = 0ull;
    for (int j = 0; j < 64; ++j) {
        if (mask_at(pmask, lane * 64 + j, mode)) pmb |= 1ull << j;
        if (mask_at(nmask, lane * 64 + j, mode)) nmb |= 1ull << j;
    }

    float lse = logf(mySe);
    float nll = lse - myLogit;
    float rinv = rsqrtf(sG[lane * 64 + lane]);

    float minp = INFINITY, maxthd = -INFINITY;
    for (int j = 0; j < 64; ++j) {
        float rj = __shfl(rinv, j, 64);
        float sim = sG[lane * 64 + j] * rinv * rj;
        sim = fminf(1.f, fmaxf(-1.f, sim));
        if (j != lane) {
            bool pm = (pmb >> j) & 1ull;
            float ps = pm ? sim : 2.0f;
            minp = fminf(minp, ps);
            maxthd = fmaxf(maxthd, pm ? sim : -2.0f);   // sentinel 2.0 -> -2.0
        }
    }
    float n_thrd = minp - NMARG;
    float p_thrd = maxthd - PMARG;

    float hps = 0.f, hns = 0.f, hpc = 0.f, hnc = 0.f;
    for (int j = 0; j < 64; ++j) {
        float rj = __shfl(rinv, j, 64);
        float sim = sG[lane * 64 + j] * rinv * rj;
        sim = fminf(1.f, fmaxf(-1.f, sim));
        if (j != lane) {
            bool pm = (pmb >> j) & 1ull;
            bool nm = (nmb >> j) & 1ull;
            float ps = pm ? sim : 2.0f;
            float ns = nm ? sim : 2.0f;
            if (ps < p_thrd) { hps += log1pf(expf(-ps)); hpc += 1.f; }
            if (ns < n_thrd) { hns += log1pf(expf(-ns)); hnc += 1.f; }
        }
    }

    float snll = wredf(nll);
    float shps = wredf(hps);
    float shns = wredf(hns);
    float shpc = wredf(hpc);
    float shnc = wredf(hnc);
    if (lane == 0) {
        float bu = snll * (1.f / 64.f);
        float hp = shpc > 0.f ? shps / shpc : 0.f;
        float hn = shnc > 0.f ? shns / shnc : 0.f;
        out[0] = bu + hp + hn;
    }
}

extern "C" void kernel_launch(void* const* d_in, const int* in_sizes, int n_in,
                              void* d_out, int out_size, void* d_ws, size_t ws_size,
                              hipStream_t stream) {
    const float* inputs = (const float*)d_in[0];
    const int* targets  = (const int*)d_in[1];
    const void* pmask   = d_in[2];
    const void* nmask   = d_in[3];
    const float* V      = (const float*)d_in[4];
    float* out = (float*)d_out;      // out[0] = loss
    float* logits = out + 1;         // out[1..] = logits [64][100000] row-major
    float* ws = (float*)d_ws;        // A-pack | Gram | se | per-ct partials

    hipLaunchKernelGGL(k_prep, dim3(65), dim3(256), 0, stream, inputs, ws);
    hipLaunchKernelGGL(k_gemm5, dim3(NGB), dim3(256), 0, stream,
                       V, ws, logits, ws);
    hipLaunchKernelGGL(k_comb, dim3(64), dim3(256), 0, stream, ws, ws);
    hipLaunchKernelGGL(k_final, dim3(1), dim3(256), 0, stream,
                       targets, pmask, nmask, logits, ws, out);
}